// Round 9
// baseline (22.419 us; speedup 1.0000x reference)
//
#include <hip/hip_runtime.h>
#include <hip/hip_bf16.h>

#define MM 512
#define LL 31
#define LDB 15
#define NPIX (MM*MM)
#define NOUT (NPIX*LDB)

#define BS1   128                  // pass1 block size (2 waves: fine barrier coupling)
#define NBLK1 (NPIX/BS1)           // 2048 pass1 blocks
#define NPART (NBLK1*2)            // per-wave partials: 4096 floats
#define NBLK2 (NPIX/256)           // 1024 pass2 blocks

typedef float f32x4 __attribute__((ext_vector_type(4)));   // native vec for nt-store

// ---- compile-time resize weight table (jax.image.resize linear, antialias) ----
struct WTab { float w[LDB][5]; int i0[LDB]; };

constexpr WTab make_wtab() {
    WTab t{};
    const double inv_scale = 31.0 / 15.0;
    const double ks = inv_scale;
    for (int k = 0; k < LDB; ++k) {
        double sf = (k + 0.5) * inv_scale - 0.5;
        double wv[LL] = {};
        double wsum = 0.0;
        for (int i = 0; i < LL; ++i) {
            double d = sf - (double)i;
            if (d < 0) d = -d;
            double w = 1.0 - d / ks;
            if (w < 0) w = 0;
            wv[i] = w;
            wsum += w;
        }
        int first = 0;
        while (first < LL && wv[first] == 0.0) ++first;
        t.i0[k] = first;
        for (int j = 0; j < 5; ++j) {
            int i = first + j;
            t.w[k][j] = (i < LL) ? (float)(wv[i] / wsum) : 0.0f;
        }
    }
    return t;
}

__constant__ WTab c_wtab = make_wtab();

__device__ __forceinline__ unsigned int enc_f32(float f) {
    unsigned int b = __float_as_uint(f);
    return (b & 0x80000000u) ? ~b : (b | 0x80000000u);
}
__device__ __forceinline__ float dec_f32(unsigned int u) {
    unsigned int b = (u & 0x80000000u) ? (u & 0x7fffffffu) : ~u;
    return __uint_as_float(b);
}

#define XT1_F  (BS1*LL)            // 3968 floats = 15.5 KB
#define XT1_V4 (XT1_F/4)           // 992
#define HT1_F  (BS1*LDB)           // 1920 floats = 7.5 KB
#define HT1_V4 (HT1_F/4)           // 480
#define HTILE_V4 (256*LDB/4)       // 960 (pass2 tile)

// async global->LDS, 16B per lane; LDS base must be wave-uniform, linear fill
__device__ __forceinline__ void async_cp16(const float4* g, const float4* l) {
    __builtin_amdgcn_global_load_lds(
        (const __attribute__((address_space(1))) void*)g,
        (__attribute__((address_space(3))) void*)l,
        16, 0, 0);
}

// ---- pass 1: 128-thread blocks, single barrier, fully-async X+H staging ----
__global__ __launch_bounds__(BS1) void pass1_async_k(const float* __restrict__ X,
                                                     const float* __restrict__ y,
                                                     const float* __restrict__ H,
                                                     float* __restrict__ r_out,
                                                     float* __restrict__ partials) {
    __shared__ float lds[XT1_F + HT1_F];   // [X: 3968][H: 1920] floats = 23 KB
    float4* lds4 = (float4*)lds;

    const int tid   = threadIdx.x;
    const int bid   = blockIdx.x;
    const int lane  = tid & 63;
    const int wbase = tid - lane;          // wave-uniform LDS anchor (float4 units)
    const int p     = bid * BS1 + tid;

    const float4* X4g = (const float4*)(X + (size_t)bid * XT1_F);
    const float4* H4g = (const float4*)(H + (size_t)bid * HT1_F);

    // ---- issue ALL staging up front, fire-and-forget ----
    // X: 992 float4 = 7*128 + 96 (tail lanes masked; dest stays linear per wave)
#pragma unroll
    for (int j = 0; j < 7; ++j)
        async_cp16(&X4g[j * BS1 + tid], &lds4[j * BS1 + wbase]);
    if (tid < XT1_V4 - 7 * BS1)            // tid < 96
        async_cp16(&X4g[7 * BS1 + tid], &lds4[7 * BS1 + wbase]);
    // H: 480 float4 = 3*128 + 96
#pragma unroll
    for (int j = 0; j < 3; ++j)
        async_cp16(&H4g[j * BS1 + tid], &lds4[XT1_V4 + j * BS1 + wbase]);
    if (tid < HT1_V4 - 3 * BS1)            // tid < 96
        async_cp16(&H4g[3 * BS1 + tid], &lds4[XT1_V4 + 3 * BS1 + wbase]);

    float yv = y[p];

    __syncthreads();   // 2-wave barrier: drains this block's staging

    // ---- spectral resize from LDS (stride 31: odd -> conflict-free) ----
    float xv[LL];
#pragma unroll
    for (int i = 0; i < LL; ++i) xv[i] = lds[tid * LL + i];

    float xr[LDB];
#pragma unroll
    for (int k = 0; k < LDB; ++k) {
        int i0 = c_wtab.i0[k];
        float s = 0.f;
#pragma unroll
        for (int j = 0; j < 5; ++j) {
            int i = i0 + j;
            if (i > LL - 1) i = LL - 1;    // weight 0 there; clamp keeps index in-bounds
            s += c_wtab.w[k][j] * xv[i];
        }
        xr[k] = s;
    }

    // ---- sensing dot-product from H region (stride 15: odd -> conflict-free) ----
    const float* hl = lds + XT1_F + tid * LDB;
    float s = 0.f, hmin = 1e30f, hmax = -1e30f;
#pragma unroll
    for (int k = 0; k < LDB; ++k) {
        float h = hl[k];
        s += h * xr[k];
        hmin = fminf(hmin, h);
        hmax = fmaxf(hmax, h);
    }
    float r = s - yv;

    r_out[p] = r;

    // per-pixel max of H*r over k (H >= 0): r>0 ? r*hmax : r*hmin
    float m = (r > 0.f) ? r * hmax : r * hmin;
#pragma unroll
    for (int off = 32; off; off >>= 1) m = fmaxf(m, __shfl_xor(m, off));
    if (lane == 0) partials[bid * 2 + (tid >> 6)] = m;   // per-wave partial, no tail barrier
}

// ---- pass 2: overlapped partials-reduce + out = H * r / max (1 barrier) ----
__global__ __launch_bounds__(256) void pass2_k(const float4* __restrict__ H4,
                                               const float* __restrict__ r_in,
                                               const float* __restrict__ partials,
                                               f32x4* __restrict__ out4) {
    __shared__ float lds_r[256];
    __shared__ float redbuf[4];

    const int tid  = threadIdx.x;
    const int bid  = blockIdx.x;
    const int wv   = tid >> 6;
    const int lane = tid & 63;

    // issue ALL loads up front so they overlap the reduce
    const float4* p4 = (const float4*)partials;        // NPART/4 = 1024 float4
    float4 a0 = p4[wv * 256 + lane];
    float4 a1 = p4[wv * 256 + 64 + lane];
    float4 a2 = p4[wv * 256 + 128 + lane];
    float4 a3 = p4[wv * 256 + 192 + lane];

    const float4* Ht = H4 + (size_t)bid * HTILE_V4;
    float4 h0 = Ht[tid];
    float4 h1 = Ht[256 + tid];
    float4 h2 = Ht[512 + tid];
    const bool has3 = tid < HTILE_V4 - 3 * 256;        // tid < 192
    float4 h3 = h0;
    if (has3) h3 = Ht[768 + tid];

    lds_r[tid] = r_in[bid * 256 + tid];

    float m = fmaxf(fmaxf(fmaxf(a0.x, a0.y), fmaxf(a0.z, a0.w)),
                    fmaxf(fmaxf(a1.x, a1.y), fmaxf(a1.z, a1.w)));
    m = fmaxf(m, fmaxf(fmaxf(a2.x, a2.y), fmaxf(a2.z, a2.w)));
    m = fmaxf(m, fmaxf(fmaxf(a3.x, a3.y), fmaxf(a3.z, a3.w)));
#pragma unroll
    for (int off = 32; off; off >>= 1) m = fmaxf(m, __shfl_xor(m, off));
    if (lane == 0) redbuf[wv] = m;
    __syncthreads();   // single barrier: covers redbuf AND lds_r
    const float inv =
        1.0f / fmaxf(fmaxf(redbuf[0], redbuf[1]), fmaxf(redbuf[2], redbuf[3]));

    f32x4* Ot = out4 + (size_t)bid * HTILE_V4;
#define EMIT(hh, qq)                                                        \
    {                                                                       \
        int q = (qq);                                                       \
        int f0 = q * 4;                                                     \
        int pl0 = f0 / LDB;                                                 \
        int rm  = f0 - pl0 * LDB;                                           \
        int pl1 = pl0 + 1; if (pl1 > 255) pl1 = 255;                        \
        float rv0 = lds_r[pl0] * inv;                                       \
        float rv1 = lds_r[pl1] * inv;                                       \
        f32x4 o;                                                            \
        o.x = (hh).x * ((rm + 0 < LDB) ? rv0 : rv1);                        \
        o.y = (hh).y * ((rm + 1 < LDB) ? rv0 : rv1);                        \
        o.z = (hh).z * ((rm + 2 < LDB) ? rv0 : rv1);                        \
        o.w = (hh).w * ((rm + 3 < LDB) ? rv0 : rv1);                        \
        __builtin_nontemporal_store(o, &Ot[q]);                             \
    }
    EMIT(h0, tid);
    EMIT(h1, 256 + tid);
    EMIT(h2, 512 + tid);
    if (has3) EMIT(h3, 768 + tid);
#undef EMIT
}

// =============== fallback path (atomic, minimal ws) ===============
#define XTILE_F  (256*LL)
#define XTILE_V4 (XTILE_F/4)
#define HTILE_F  (256*LDB)

__global__ __launch_bounds__(256) void pass1_atomic_k(const float* __restrict__ X,
                                                      const float* __restrict__ y,
                                                      const float* __restrict__ H,
                                                      float* __restrict__ xn_out,
                                                      unsigned int* __restrict__ gmax_atomic) {
    __shared__ float lds[XTILE_F];
    float4* lds4 = (float4*)lds;

    const int tid = threadIdx.x;
    const int p   = blockIdx.x * 256 + tid;

    float yv = y[p];

    {
        const float4* X4 = (const float4*)(X + (size_t)blockIdx.x * XTILE_F);
#pragma unroll
        for (int j = 0; j < 7; ++j)
            lds4[j * 256 + tid] = X4[j * 256 + tid];
        if (tid < XTILE_V4 - 7 * 256)
            lds4[7 * 256 + tid] = X4[7 * 256 + tid];
    }
    __syncthreads();

    float xv[LL];
#pragma unroll
    for (int i = 0; i < LL; ++i) xv[i] = lds[tid * LL + i];

    float xr[LDB];
#pragma unroll
    for (int k = 0; k < LDB; ++k) {
        int i0 = c_wtab.i0[k];
        float s = 0.f;
#pragma unroll
        for (int j = 0; j < 5; ++j) {
            int i = i0 + j;
            if (i > LL - 1) i = LL - 1;
            s += c_wtab.w[k][j] * xv[i];
        }
        xr[k] = s;
    }
    __syncthreads();

    {
        const float4* H4 = (const float4*)(H + (size_t)blockIdx.x * HTILE_F);
#pragma unroll
        for (int j = 0; j < 3; ++j)
            lds4[j * 256 + tid] = H4[j * 256 + tid];
        if (tid < (HTILE_F/4) - 3 * 256)
            lds4[3 * 256 + tid] = H4[3 * 256 + tid];
    }
    __syncthreads();

    float s = 0.f, hmin = 1e30f, hmax = -1e30f;
#pragma unroll
    for (int k = 0; k < LDB; ++k) {
        float h = lds[tid * LDB + k];
        s += h * xr[k];
        hmin = fminf(hmin, h);
        hmax = fmaxf(hmax, h);
    }
    float r = s - yv;

    float* op = xn_out + (size_t)p * LDB;
#pragma unroll
    for (int k = 0; k < LDB; ++k) op[k] = lds[tid * LDB + k] * r;

    float m = (r > 0.f) ? r * hmax : r * hmin;
#pragma unroll
    for (int off = 32; off; off >>= 1) m = fmaxf(m, __shfl_xor(m, off));
    if ((tid & 63) == 0) atomicMax(gmax_atomic, enc_f32(m));
}

__global__ __launch_bounds__(256) void pass2_inplace_k(float* __restrict__ out,
                                                       const unsigned int* __restrict__ gmax) {
    float inv = 1.0f / dec_f32(*gmax);
    int idx = blockIdx.x * blockDim.x + threadIdx.x;
    if (idx >= NOUT) return;
    out[idx] *= inv;
}

extern "C" void kernel_launch(void* const* d_in, const int* in_sizes, int n_in,
                              void* d_out, int out_size, void* d_ws, size_t ws_size,
                              hipStream_t stream) {
    const float* X = (const float*)d_in[0];
    const float* y = (const float*)d_in[1];
    const float* H = (const float*)d_in[2];
    float* out = (float*)d_out;

    // ws layout: [0,256)=gmax  [256, 256+16K)=partials(4096 f)  [256+16K, ...)=r_buf
    unsigned int* gmax_u  = (unsigned int*)d_ws;
    float* partials = (float*)((char*)d_ws + 256);
    float* r_buf    = (float*)((char*)d_ws + 256 + (size_t)NPART * sizeof(float));

    const int g2s = (NOUT + 255) / 256;

    size_t need = 256 + (size_t)NPART * 4 + (size_t)NPIX * 4;
    if (ws_size >= need) {
        pass1_async_k<<<NBLK1, BS1, 0, stream>>>(X, y, H, r_buf, partials);
        pass2_k<<<NBLK2, 256, 0, stream>>>((const float4*)H, r_buf, partials, (f32x4*)out);
    } else {
        (void)hipMemsetAsync(d_ws, 0, 256, stream);
        pass1_atomic_k<<<NBLK2, 256, 0, stream>>>(X, y, H, out, gmax_u);
        pass2_inplace_k<<<g2s, 256, 0, stream>>>(out, gmax_u);
    }
}

// Round 10
// 18.688 us; speedup vs baseline: 1.1996x; 1.1996x over previous
//
#include <hip/hip_runtime.h>
#include <hip/hip_bf16.h>

#define MM 512
#define LL 31
#define LDB 15
#define NPIX (MM*MM)
#define NOUT (NPIX*LDB)
#define NBLK1 (NPIX/256)   // 1024 pass1 blocks (256 thr)
#define NPART (NBLK1*4)    // per-wave partials: 4096 floats
#define NBLK2 (NPIX/256)   // 1024 pass2 blocks
#define HTILE_V4 (256*LDB/4)  // 960 (pass2 tile)

typedef float f32x4 __attribute__((ext_vector_type(4)));   // native vec for nt-store

// ---- compile-time resize weight table (jax.image.resize linear, antialias) ----
struct WTab { float w[LDB][5]; int i0[LDB]; };

constexpr WTab make_wtab() {
    WTab t{};
    const double inv_scale = 31.0 / 15.0;
    const double ks = inv_scale;
    for (int k = 0; k < LDB; ++k) {
        double sf = (k + 0.5) * inv_scale - 0.5;
        double wv[LL] = {};
        double wsum = 0.0;
        for (int i = 0; i < LL; ++i) {
            double d = sf - (double)i;
            if (d < 0) d = -d;
            double w = 1.0 - d / ks;
            if (w < 0) w = 0;
            wv[i] = w;
            wsum += w;
        }
        int first = 0;
        while (first < LL && wv[first] == 0.0) ++first;
        t.i0[k] = first;
        for (int j = 0; j < 5; ++j) {
            int i = first + j;
            t.w[k][j] = (i < LL) ? (float)(wv[i] / wsum) : 0.0f;
        }
    }
    return t;
}

__constant__ WTab c_wtab = make_wtab();

__device__ __forceinline__ unsigned int enc_f32(float f) {
    unsigned int b = __float_as_uint(f);
    return (b & 0x80000000u) ? ~b : (b | 0x80000000u);
}
__device__ __forceinline__ float dec_f32(unsigned int u) {
    unsigned int b = (u & 0x80000000u) ? (u & 0x7fffffffu) : ~u;
    return __uint_as_float(b);
}

// ---- pass 1 (register-direct): no LDS, no barriers ----
// Each thread loads its own contiguous X row (31 f) and H row (15 f) into
// registers. Wave footprint is one contiguous 7.9 KB region: every 128 B
// line is fetched once, later dword hits are L1. Zero sync in the kernel.
__global__ __launch_bounds__(256) void pass1_reg_k(const float* __restrict__ X,
                                                   const float* __restrict__ y,
                                                   const float* __restrict__ H,
                                                   float* __restrict__ r_out,
                                                   float* __restrict__ partials) {
    const int tid  = threadIdx.x;
    const int bid  = blockIdx.x;
    const int lane = tid & 63;
    const int p    = bid * 256 + tid;   // grid exact: 1024*256 = NPIX

    const float* xp = X + (size_t)p * LL;
    const float* hp = H + (size_t)p * LDB;

    float xv[LL];
#pragma unroll
    for (int i = 0; i < LL; ++i) xv[i] = xp[i];

    float hv[LDB];
#pragma unroll
    for (int k = 0; k < LDB; ++k) hv[k] = hp[k];

    float yv = y[p];

    float s = 0.f, hmin = 1e30f, hmax = -1e30f;
#pragma unroll
    for (int k = 0; k < LDB; ++k) {
        int i0 = c_wtab.i0[k];
        float xr = 0.f;
#pragma unroll
        for (int j = 0; j < 5; ++j) {
            int i = i0 + j;
            if (i > LL - 1) i = LL - 1;    // weight 0 there; clamp keeps index in-bounds
            xr += c_wtab.w[k][j] * xv[i];
        }
        float h = hv[k];
        s += h * xr;
        hmin = fminf(hmin, h);
        hmax = fmaxf(hmax, h);
    }
    float r = s - yv;

    r_out[p] = r;

    // per-pixel max of H*r over k (H >= 0): r>0 ? r*hmax : r*hmin
    float m = (r > 0.f) ? r * hmax : r * hmin;
#pragma unroll
    for (int off = 32; off; off >>= 1) m = fmaxf(m, __shfl_xor(m, off));
    if (lane == 0) partials[bid * 4 + (tid >> 6)] = m;   // per-wave partial
}

// ---- pass 2: overlapped partials-reduce + out = H * r / max (1 barrier) ----
__global__ __launch_bounds__(256) void pass2_k(const float4* __restrict__ H4,
                                               const float* __restrict__ r_in,
                                               const float* __restrict__ partials,
                                               f32x4* __restrict__ out4) {
    __shared__ float lds_r[256];
    __shared__ float redbuf[4];

    const int tid  = threadIdx.x;
    const int bid  = blockIdx.x;
    const int wv   = tid >> 6;
    const int lane = tid & 63;

    // issue ALL loads up front so they overlap the reduce
    const float4* p4 = (const float4*)partials;        // NPART/4 = 1024 float4
    float4 a0 = p4[wv * 256 + lane];
    float4 a1 = p4[wv * 256 + 64 + lane];
    float4 a2 = p4[wv * 256 + 128 + lane];
    float4 a3 = p4[wv * 256 + 192 + lane];

    const float4* Ht = H4 + (size_t)bid * HTILE_V4;
    float4 h0 = Ht[tid];
    float4 h1 = Ht[256 + tid];
    float4 h2 = Ht[512 + tid];
    const bool has3 = tid < HTILE_V4 - 3 * 256;        // tid < 192
    float4 h3 = h0;
    if (has3) h3 = Ht[768 + tid];

    lds_r[tid] = r_in[bid * 256 + tid];

    float m = fmaxf(fmaxf(fmaxf(a0.x, a0.y), fmaxf(a0.z, a0.w)),
                    fmaxf(fmaxf(a1.x, a1.y), fmaxf(a1.z, a1.w)));
    m = fmaxf(m, fmaxf(fmaxf(a2.x, a2.y), fmaxf(a2.z, a2.w)));
    m = fmaxf(m, fmaxf(fmaxf(a3.x, a3.y), fmaxf(a3.z, a3.w)));
#pragma unroll
    for (int off = 32; off; off >>= 1) m = fmaxf(m, __shfl_xor(m, off));
    if (lane == 0) redbuf[wv] = m;
    __syncthreads();   // single barrier: covers redbuf AND lds_r
    const float inv =
        1.0f / fmaxf(fmaxf(redbuf[0], redbuf[1]), fmaxf(redbuf[2], redbuf[3]));

    f32x4* Ot = out4 + (size_t)bid * HTILE_V4;
#define EMIT(hh, qq)                                                        \
    {                                                                       \
        int q = (qq);                                                       \
        int f0 = q * 4;                                                     \
        int pl0 = f0 / LDB;                                                 \
        int rm  = f0 - pl0 * LDB;                                           \
        int pl1 = pl0 + 1; if (pl1 > 255) pl1 = 255;                        \
        float rv0 = lds_r[pl0] * inv;                                       \
        float rv1 = lds_r[pl1] * inv;                                       \
        f32x4 o;                                                            \
        o.x = (hh).x * ((rm + 0 < LDB) ? rv0 : rv1);                        \
        o.y = (hh).y * ((rm + 1 < LDB) ? rv0 : rv1);                        \
        o.z = (hh).z * ((rm + 2 < LDB) ? rv0 : rv1);                        \
        o.w = (hh).w * ((rm + 3 < LDB) ? rv0 : rv1);                        \
        __builtin_nontemporal_store(o, &Ot[q]);                             \
    }
    EMIT(h0, tid);
    EMIT(h1, 256 + tid);
    EMIT(h2, 512 + tid);
    if (has3) EMIT(h3, 768 + tid);
#undef EMIT
}

// =============== fallback path (atomic, minimal ws) ===============
__global__ __launch_bounds__(256) void pass1_atomic_k(const float* __restrict__ X,
                                                      const float* __restrict__ y,
                                                      const float* __restrict__ H,
                                                      float* __restrict__ xn_out,
                                                      unsigned int* __restrict__ gmax_atomic) {
    const int tid = threadIdx.x;
    const int p   = blockIdx.x * 256 + tid;

    const float* xp = X + (size_t)p * LL;
    const float* hp = H + (size_t)p * LDB;

    float xv[LL];
#pragma unroll
    for (int i = 0; i < LL; ++i) xv[i] = xp[i];

    float hv[LDB];
#pragma unroll
    for (int k = 0; k < LDB; ++k) hv[k] = hp[k];

    float yv = y[p];

    float s = 0.f, hmin = 1e30f, hmax = -1e30f;
#pragma unroll
    for (int k = 0; k < LDB; ++k) {
        int i0 = c_wtab.i0[k];
        float xr = 0.f;
#pragma unroll
        for (int j = 0; j < 5; ++j) {
            int i = i0 + j;
            if (i > LL - 1) i = LL - 1;
            xr += c_wtab.w[k][j] * xv[i];
        }
        float h = hv[k];
        s += h * xr;
        hmin = fminf(hmin, h);
        hmax = fmaxf(hmax, h);
    }
    float r = s - yv;

    float* op = xn_out + (size_t)p * LDB;
#pragma unroll
    for (int k = 0; k < LDB; ++k) op[k] = hv[k] * r;

    float m = (r > 0.f) ? r * hmax : r * hmin;
#pragma unroll
    for (int off = 32; off; off >>= 1) m = fmaxf(m, __shfl_xor(m, off));
    if ((tid & 63) == 0) atomicMax(gmax_atomic, enc_f32(m));
}

__global__ __launch_bounds__(256) void pass2_inplace_k(float* __restrict__ out,
                                                       const unsigned int* __restrict__ gmax) {
    float inv = 1.0f / dec_f32(*gmax);
    int idx = blockIdx.x * blockDim.x + threadIdx.x;
    if (idx >= NOUT) return;
    out[idx] *= inv;
}

extern "C" void kernel_launch(void* const* d_in, const int* in_sizes, int n_in,
                              void* d_out, int out_size, void* d_ws, size_t ws_size,
                              hipStream_t stream) {
    const float* X = (const float*)d_in[0];
    const float* y = (const float*)d_in[1];
    const float* H = (const float*)d_in[2];
    float* out = (float*)d_out;

    // ws layout: [0,256)=gmax  [256, 256+16K)=partials(4096 f)  [256+16K, ...)=r_buf
    unsigned int* gmax_u  = (unsigned int*)d_ws;
    float* partials = (float*)((char*)d_ws + 256);
    float* r_buf    = (float*)((char*)d_ws + 256 + (size_t)NPART * sizeof(float));

    const int g2s = (NOUT + 255) / 256;

    size_t need = 256 + (size_t)NPART * 4 + (size_t)NPIX * 4;
    if (ws_size >= need) {
        pass1_reg_k<<<NBLK1, 256, 0, stream>>>(X, y, H, r_buf, partials);
        pass2_k<<<NBLK2, 256, 0, stream>>>((const float4*)H, r_buf, partials, (f32x4*)out);
    } else {
        (void)hipMemsetAsync(d_ws, 0, 256, stream);
        pass1_atomic_k<<<NBLK2, 256, 0, stream>>>(X, y, H, out, gmax_u);
        pass2_inplace_k<<<g2s, 256, 0, stream>>>(out, gmax_u);
    }
}